// Round 2
// baseline (633.899 us; speedup 1.0000x reference)
//
#include <hip/hip_runtime.h>
#include <stdint.h>
#include <stddef.h>

// ---------------------------------------------------------------------------
// out[b,t,f] = x @ (w + 2.0 * lora_a @ lora_b)     (LoRA folded into weight)
// M = 8192 (B*T), K = 2048 (D), N = 8192 (F). fp32 in/out, bf16 MFMA compute.
// GEMM: 256x256 8-phase, counted vmcnt(6) (3 half-tiles in flight), NT C-stores.
// ---------------------------------------------------------------------------

typedef __bf16 bf16;
typedef __bf16 bf16x4 __attribute__((ext_vector_type(4)));
typedef __bf16 bf16x8 __attribute__((ext_vector_type(8)));
typedef float  f32x4  __attribute__((ext_vector_type(4)));

#define M_DIM 8192
#define N_DIM 8192
#define K_DIM 2048
#define LRANK 16
#define LSCALE 2.0f

#define BM 256
#define BN 256
#define BK 64
#define NT (K_DIM / BK)          // 32 K-tiles, 16 iterations of 2

typedef __attribute__((address_space(1))) void* as1_void;
typedef __attribute__((address_space(3))) void* as3_void;

__device__ __forceinline__ void gload_lds16(const void* g, void* l) {
    // async global->LDS, 16 bytes per lane; LDS dst is wave-uniform base + lane*16.
    __builtin_amdgcn_global_load_lds((as1_void)(g), (as3_void)(l), 16, 0, 0);
}

// ---------------------------------------------------------------------------
// Kernel 1: x fp32 -> bf16, straight convert. 4 elems/thread.
// ---------------------------------------------------------------------------
__global__ void convert_x_kernel(const float* __restrict__ x,
                                 bf16* __restrict__ xb) {
    int i = (blockIdx.x * blockDim.x + threadIdx.x) * 4;
    float4 v = *(const float4*)(x + i);
    bf16x4 o;
    o.x = (bf16)v.x; o.y = (bf16)v.y; o.z = (bf16)v.z; o.w = (bf16)v.w;
    *(bf16x4*)(xb + i) = o;
}

// ---------------------------------------------------------------------------
// Kernel 2: Wt[n][k] = bf16( w[k][n] + 2.0 * sum_L a[k][L]*b[L][n] )
// 32x32 tile transpose through LDS; coalesced loads AND stores.
// ---------------------------------------------------------------------------
__global__ void fold_transpose_kernel(const float* __restrict__ w,   // [K][N]
                                      const float* __restrict__ la,  // [K][16]
                                      const float* __restrict__ lb,  // [16][N]
                                      bf16* __restrict__ wt) {       // [N][K]
    __shared__ float tile[32][33];
    __shared__ float at[32][17];
    __shared__ float bt[16][32];

    const int k0 = blockIdx.x * 32;
    const int n0 = blockIdx.y * 32;
    const int t  = threadIdx.x;      // 256 threads
    const int c  = t & 31;
    const int r0 = t >> 5;           // 0..7

    #pragma unroll
    for (int rr = 0; rr < 32; rr += 8)
        tile[r0 + rr][c] = w[(size_t)(k0 + r0 + rr) * N_DIM + n0 + c];

    at[t >> 4][t & 15]          = la[(size_t)(k0 + (t >> 4)) * LRANK + (t & 15)];
    at[(t + 256) >> 4][t & 15]  = la[(size_t)(k0 + ((t + 256) >> 4)) * LRANK + (t & 15)];

    bt[t >> 5][c]       = lb[(size_t)(t >> 5) * N_DIM + n0 + c];
    bt[(t >> 5) + 8][c] = lb[(size_t)((t >> 5) + 8) * N_DIM + n0 + c];

    __syncthreads();

    #pragma unroll
    for (int rr = 0; rr < 32; rr += 8) {
        const int nl = r0 + rr;
        const int kl = c;
        float delta = 0.f;
        #pragma unroll
        for (int L = 0; L < LRANK; ++L)
            delta += at[kl][L] * bt[L][nl];
        float v = tile[kl][nl] + LSCALE * delta;
        wt[(size_t)(n0 + nl) * K_DIM + k0 + kl] = (bf16)v;
    }
}

// ---------------------------------------------------------------------------
// Kernel 3: C[M][N] = A[M][K] * Bt[N][K]^T  — 256x256 tile, 8-phase schedule.
//
// 8 waves, 2(M)x4(N). Quadrant order per tile: Q1=A0xB0 Q2=A0xB1 Q3=A1xB0
// Q4=A1xB1 (A-frags reused across Q1->Q2 and Q3->Q4).
//
// Stage schedule: ONE half-tile per phase, 3 half-tiles ahead (m201's vmcnt(6)):
//   consumption of tile u: staged at [P-3, P-2, P-1, P] relative to the wait
//   that certifies it.  Per iteration (tile t in buf0 at P1-4, t+1 in buf1
//   at P5-8):
//     P1: A1(t+1)->buf1   P2: A0(t+2)->buf0   P3: B0(t+2)->buf0
//     P4: B1(t+2)->buf0 + vmcnt(6)            P5: A1(t+2)->buf0
//     P6: A0(t+3)->buf1   P7: B0(t+3)->buf1   P8: B1(t+3)->buf1 + vmcnt(6)
//   vmcnt(6) at P4 certifies through P1's stage (= all of tile t+1, staged
//   P6'/P7'/P8'/P1), leaving the newest 3 half-tiles (6 loads) in flight.
//   vmcnt(6) at P8 certifies through P5 (= all of tile t+2).
//   WAR: every stage lands >= 1 full barrier after its region's last ds_read
//   (A0 read P1, B0 read P1, B1 read P2, A1 read P3; stages at P2,P3,P4,P5
//   of the NEXT tile's window — verified per phase, incl. clamped tail).
// ---------------------------------------------------------------------------

#define BAR()   __builtin_amdgcn_s_barrier()
#define WAITL() do { asm volatile("s_waitcnt lgkmcnt(0)" ::: "memory"); \
                     __builtin_amdgcn_sched_barrier(0); } while (0)
#define WAITL8() asm volatile("s_waitcnt lgkmcnt(8)" ::: "memory")
#define WAITV6() asm volatile("s_waitcnt vmcnt(6)" ::: "memory")
#define PRHI()  __builtin_amdgcn_s_setprio(1)
#define PRLO()  __builtin_amdgcn_s_setprio(0)

#define STAGE_A(t, h, buf) do {                                                   \
    _Pragma("unroll")                                                             \
    for (int c_ = 0; c_ < 2; ++c_)                                                \
        gload_lds16(aG + (size_t)((h) * 128 + prow[c_]) * K_DIM + (t) * BK + pcl[c_] * 8, \
                    As + (buf) * (BM * BK) + (h) * 8192 + c_ * 4096 + tid * 8);   \
} while (0)

#define STAGE_B(t, h, buf) do {                                                   \
    _Pragma("unroll")                                                             \
    for (int c_ = 0; c_ < 2; ++c_)                                                \
        gload_lds16(bG + (size_t)((h) * 128 + prow[c_]) * K_DIM + (t) * BK + pcl[c_] * 8, \
                    Bs + (buf) * (BN * BK) + (h) * 8192 + c_ * 4096 + tid * 8);   \
} while (0)

#define RD_A(grp, buf) do {                                                       \
    _Pragma("unroll")                                                             \
    for (int q_ = 0; q_ < 4; ++q_) {                                              \
        af[q_][0] = *(const bf16x8*)(As + (buf) * (BM * BK) + baseA[(grp) + q_]); \
        af[q_][1] = *(const bf16x8*)(As + (buf) * (BM * BK) + (baseA[(grp) + q_] ^ 32)); \
    }                                                                             \
} while (0)

#define RD_B(dst, jlo, buf) do {                                                  \
    _Pragma("unroll")                                                             \
    for (int q_ = 0; q_ < 2; ++q_) {                                              \
        dst[q_][0] = *(const bf16x8*)(Bs + (buf) * (BN * BK) + baseB[(jlo) + q_]);\
        dst[q_][1] = *(const bf16x8*)(Bs + (buf) * (BN * BK) + (baseB[(jlo) + q_] ^ 32)); \
    }                                                                             \
} while (0)

#define MMQ(I0, J0, BF) do {                                                      \
    _Pragma("unroll")                                                             \
    for (int q_ = 0; q_ < 4; ++q_)                                                \
        _Pragma("unroll")                                                         \
        for (int jj_ = 0; jj_ < 2; ++jj_)                                         \
            _Pragma("unroll")                                                     \
            for (int ks_ = 0; ks_ < 2; ++ks_)                                     \
                acc[(I0) + q_][(J0) + jj_] = __builtin_amdgcn_mfma_f32_16x16x32_bf16( \
                    af[q_][ks_], BF[jj_][ks_], acc[(I0) + q_][(J0) + jj_], 0, 0, 0);  \
} while (0)

__global__ __launch_bounds__(512, 2)
void gemm_bf16_kernel(const bf16* __restrict__ A,   // [M][K]
                      const bf16* __restrict__ Bt,  // [N][K]
                      float* __restrict__ C) {      // [M][N]
    __shared__ __align__(16) bf16 As[2 * BM * BK];  // 64 KB (2 bufs x 256x64)
    __shared__ __align__(16) bf16 Bs[2 * BN * BK];  // 64 KB

    const int tid  = threadIdx.x;        // 0..511
    const int lane = tid & 63;
    const int wave = tid >> 6;           // 0..7
    const int wm   = (wave >> 2) * 64;   // 0 / 64
    const int wn   = (wave & 3) * 32;    // 0 / 32 / 64 / 96

    // T1: XCD-aware swizzle over the 32x32 block grid (1024 % 8 == 0)
    const int id  = blockIdx.y * 32 + blockIdx.x;
    const int swz = (id & 7) * 128 + (id >> 3);
    const int m0  = (swz >> 5) * BM;
    const int n0  = (swz & 31) * BN;

    // staging descriptors: physical chunk cp at (row,cp) holds k-chunk cp^(row&7)
    int prow[2], pcl[2];
    #pragma unroll
    for (int c = 0; c < 2; ++c) {
        int p   = c * 8192 + tid * 16;   // byte pos within a 16 KB half-tile
        prow[c] = p >> 7;                // 128 B per row
        pcl[c]  = ((p >> 4) & 7) ^ (prow[c] & 7);
    }
    const bf16* aG = A  + (size_t)m0 * K_DIM;
    const bf16* bG = Bt + (size_t)n0 * K_DIM;

    // fragment base offsets (ks=0); ks toggles elem-bit5 (XOR 32)
    int baseA[8], baseB[4];
    #pragma unroll
    for (int i = 0; i < 8; ++i) {
        int ra = ((i & 4) ? 128 : 0) + wm + (i & 3) * 16 + (lane & 15);
        baseA[i] = ra * 64 + (((lane >> 4) ^ (ra & 7)) * 8);
    }
    #pragma unroll
    for (int j = 0; j < 4; ++j) {
        int rb = ((j & 2) ? 128 : 0) + wn + (j & 1) * 16 + (lane & 15);
        baseB[j] = rb * 64 + (((lane >> 4) ^ (rb & 7)) * 8);
    }

    f32x4 acc[8][4] = {};
    bf16x8 af[4][2], bA[2][2], bBv[2][2];

    // prologue: tile0 (4 halves) + tile1 A0,B0,B1 = 7 half-tiles, 14 loads.
    // vmcnt(6) certifies tile0; tile1's 3 staged halves stay in flight.
    STAGE_A(0, 0, 0); STAGE_B(0, 0, 0);
    STAGE_B(0, 1, 0); STAGE_A(0, 1, 0);
    STAGE_A(1, 0, 1); STAGE_B(1, 0, 1); STAGE_B(1, 1, 1);
    WAITV6();
    BAR();

    for (int it = 0; it < NT / 2; ++it) {
        const int t1 = 2 * it + 1;
        const int t2 = (2 * it + 2 < NT) ? 2 * it + 2 : NT - 1;
        const int t3 = (2 * it + 3 < NT) ? 2 * it + 3 : NT - 1;

        // ---------------- tile 2it from buf0 ----------------
        // P1: Q1 = A0 x B0
        RD_A(0, 0); RD_B(bA, 0, 0);
        STAGE_A(t1, 1, 1);                 // A1(t+1) -> buf1
        WAITL8();
        BAR(); WAITL(); PRHI(); MMQ(0, 0, bA); PRLO(); BAR();
        // P2: Q2 = A0 x B1
        RD_B(bBv, 2, 0);
        STAGE_A(t2, 0, 0);                 // A0(t+2) -> buf0
        BAR(); WAITL(); PRHI(); MMQ(0, 2, bBv); PRLO(); BAR();
        // P3: Q3 = A1 x B0
        RD_A(4, 0);
        STAGE_B(t2, 0, 0);                 // B0(t+2) -> buf0
        BAR(); WAITL(); PRHI(); MMQ(4, 0, bA); PRLO(); BAR();
        // P4: Q4 = A1 x B1 (no new ds_reads)
        STAGE_B(t2, 1, 0);                 // B1(t+2) -> buf0
        WAITV6();                          // certifies all 4 halves of tile t+1
        BAR(); PRHI(); MMQ(4, 2, bBv); PRLO(); BAR();

        // ---------------- tile 2it+1 from buf1 ----------------
        // P5: Q1
        RD_A(0, 1); RD_B(bA, 0, 1);
        STAGE_A(t2, 1, 0);                 // A1(t+2) -> buf0
        WAITL8();
        BAR(); WAITL(); PRHI(); MMQ(0, 0, bA); PRLO(); BAR();
        // P6: Q2
        RD_B(bBv, 2, 1);
        STAGE_A(t3, 0, 1);                 // A0(t+3) -> buf1
        BAR(); WAITL(); PRHI(); MMQ(0, 2, bBv); PRLO(); BAR();
        // P7: Q3
        RD_A(4, 1);
        STAGE_B(t3, 0, 1);                 // B0(t+3) -> buf1
        BAR(); WAITL(); PRHI(); MMQ(4, 0, bA); PRLO(); BAR();
        // P8: Q4
        STAGE_B(t3, 1, 1);                 // B1(t+3) -> buf1
        WAITV6();                          // certifies all 4 halves of tile t+2
        BAR(); PRHI(); MMQ(4, 2, bBv); PRLO(); BAR();
    }

    // epilogue: C/D layout col = lane&15, row = (lane>>4)*4 + reg.
    // Nontemporal: C is write-once — keep it out of L2/L3 so A/B panels stay
    // resident (FETCH_SIZE was 8.5x the input footprint from C-stream thrash).
    const int cr = (lane >> 4) * 4;
    const int cc = lane & 15;
    #pragma unroll
    for (int i = 0; i < 8; ++i) {
        const int row = m0 + ((i & 4) ? 128 : 0) + wm + (i & 3) * 16 + cr;
        #pragma unroll
        for (int j = 0; j < 4; ++j) {
            const int col = n0 + ((j & 2) ? 128 : 0) + wn + (j & 1) * 16 + cc;
            float* cp = C + (size_t)row * N_DIM + col;
            #pragma unroll
            for (int r = 0; r < 4; ++r)
                __builtin_nontemporal_store(acc[i][j][r], cp + (size_t)r * N_DIM);
        }
    }
}

// ---------------------------------------------------------------------------
extern "C" void kernel_launch(void* const* d_in, const int* in_sizes, int n_in,
                              void* d_out, int out_size, void* d_ws, size_t ws_size,
                              hipStream_t stream) {
    const float* x  = (const float*)d_in[0];   // [B,T,D] = [8192, 2048]
    const float* w  = (const float*)d_in[1];   // [D, F]  = [2048, 8192]
    const float* la = (const float*)d_in[2];   // [D, 16]
    const float* lb = (const float*)d_in[3];   // [16, F]
    float* out = (float*)d_out;                // [8192, 8192]

    bf16* xb = (bf16*)d_ws;                                        // 32 MB
    bf16* wt = (bf16*)((char*)d_ws + (size_t)M_DIM * K_DIM * 2);   // 32 MB

    convert_x_kernel<<<M_DIM * K_DIM / 4 / 256, 256, 0, stream>>>(x, xb);
    fold_transpose_kernel<<<dim3(K_DIM / 32, N_DIM / 32), 256, 0, stream>>>(w, la, lb, wt);
    gemm_bf16_kernel<<<dim3(N_DIM / BN, M_DIM / BM), 512, 0, stream>>>(xb, wt, out);
}

// Round 5
// 608.399 us; speedup vs baseline: 1.0419x; 1.0419x over previous
//
#include <hip/hip_runtime.h>
#include <stdint.h>
#include <stddef.h>

// ---------------------------------------------------------------------------
// out[b,t,f] = x @ (w + 2.0 * lora_a @ lora_b)     (LoRA folded into weight)
// M = 8192 (B*T), K = 2048 (D), N = 8192 (F). fp32 in/out, bf16 MFMA compute.
// GEMM: 256x256 8-phase, counted vmcnt(6), inline-asm ds_read_b128 fragment
// loads with hand-counted lgkmcnt (derived-waits port — keeps the compiler
// from inserting alias-driven vmcnt drains between global_load_lds and the
// LDS fragment reads).
// ---------------------------------------------------------------------------

typedef __bf16 bf16;
typedef __bf16 bf16x4 __attribute__((ext_vector_type(4)));
typedef __bf16 bf16x8 __attribute__((ext_vector_type(8)));
typedef float  f32x4  __attribute__((ext_vector_type(4)));
typedef unsigned int u32x4 __attribute__((ext_vector_type(4)));

#define M_DIM 8192
#define N_DIM 8192
#define K_DIM 2048
#define LRANK 16
#define LSCALE 2.0f

#define BM 256
#define BN 256
#define BK 64
#define NT (K_DIM / BK)          // 32 K-tiles, 16 iterations of 2

typedef __attribute__((address_space(1))) void* as1_void;
typedef __attribute__((address_space(3))) void* as3_void;

__device__ __forceinline__ void gload_lds16(const void* g, void* l) {
    // async global->LDS, 16 bytes per lane; LDS dst is wave-uniform base + lane*16.
    __builtin_amdgcn_global_load_lds((as1_void)(g), (as3_void)(l), 16, 0, 0);
}

// Opaque LDS reads: compiler cannot see these touch LDS, so it cannot insert
// conservative vmcnt waits against the in-flight global_load_lds DMA.  All
// ordering is hand-managed: issue -> (barrier) -> s_waitcnt lgkmcnt(0) ->
// sched_barrier(0) -> MFMA.  Output typed u32x4 (standard tuple constraint),
// early-clobber so dest never aliases the address VGPR.
__device__ __forceinline__ bf16x8 dsr_b0(unsigned addr) {
    u32x4 r;
    asm volatile("ds_read_b128 %0, %1" : "=&v"(r) : "v"(addr));
    return __builtin_bit_cast(bf16x8, r);
}
__device__ __forceinline__ bf16x8 dsr_b1(unsigned addr) {
    u32x4 r;
    asm volatile("ds_read_b128 %0, %1 offset:32768" : "=&v"(r) : "v"(addr));
    return __builtin_bit_cast(bf16x8, r);
}
#define DSR(addr, buf) ((buf) ? dsr_b1(addr) : dsr_b0(addr))

// ---------------------------------------------------------------------------
// Kernel 1: x fp32 -> bf16, straight convert. 4 elems/thread.
// ---------------------------------------------------------------------------
__global__ void convert_x_kernel(const float* __restrict__ x,
                                 bf16* __restrict__ xb) {
    int i = (blockIdx.x * blockDim.x + threadIdx.x) * 4;
    float4 v = *(const float4*)(x + i);
    bf16x4 o;
    o.x = (bf16)v.x; o.y = (bf16)v.y; o.z = (bf16)v.z; o.w = (bf16)v.w;
    *(bf16x4*)(xb + i) = o;
}

// ---------------------------------------------------------------------------
// Kernel 2: Wt[n][k] = bf16( w[k][n] + 2.0 * sum_L a[k][L]*b[L][n] )
// 32x32 tile transpose through LDS; coalesced loads AND stores.
// ---------------------------------------------------------------------------
__global__ void fold_transpose_kernel(const float* __restrict__ w,   // [K][N]
                                      const float* __restrict__ la,  // [K][16]
                                      const float* __restrict__ lb,  // [16][N]
                                      bf16* __restrict__ wt) {       // [N][K]
    __shared__ float tile[32][33];
    __shared__ float at[32][17];
    __shared__ float bt[16][32];

    const int k0 = blockIdx.x * 32;
    const int n0 = blockIdx.y * 32;
    const int t  = threadIdx.x;      // 256 threads
    const int c  = t & 31;
    const int r0 = t >> 5;           // 0..7

    #pragma unroll
    for (int rr = 0; rr < 32; rr += 8)
        tile[r0 + rr][c] = w[(size_t)(k0 + r0 + rr) * N_DIM + n0 + c];

    at[t >> 4][t & 15]          = la[(size_t)(k0 + (t >> 4)) * LRANK + (t & 15)];
    at[(t + 256) >> 4][t & 15]  = la[(size_t)(k0 + ((t + 256) >> 4)) * LRANK + (t & 15)];

    bt[t >> 5][c]       = lb[(size_t)(t >> 5) * N_DIM + n0 + c];
    bt[(t >> 5) + 8][c] = lb[(size_t)((t >> 5) + 8) * N_DIM + n0 + c];

    __syncthreads();

    #pragma unroll
    for (int rr = 0; rr < 32; rr += 8) {
        const int nl = r0 + rr;
        const int kl = c;
        float delta = 0.f;
        #pragma unroll
        for (int L = 0; L < LRANK; ++L)
            delta += at[kl][L] * bt[L][nl];
        float v = tile[kl][nl] + LSCALE * delta;
        wt[(size_t)(n0 + nl) * K_DIM + k0 + kl] = (bf16)v;
    }
}

// ---------------------------------------------------------------------------
// Kernel 3: C[M][N] = A[M][K] * Bt[N][K]^T  — 256x256 tile, 8-phase schedule.
//
// 8 waves, 2(M)x4(N). Quadrant order per tile: Q1=A0xB0 Q2=A0xB1 Q3=A1xB0
// Q4=A1xB1 (A-frags reused across Q1->Q2 and Q3->Q4).
//
// Stage schedule: ONE half-tile per phase, 3 half-tiles in flight (vmcnt(6)):
//     P1: A1(t+1)->buf1   P2: A0(t+2)->buf0   P3: B0(t+2)->buf0
//     P4: B1(t+2)->buf0 + vmcnt(6)            P5: A1(t+2)->buf0
//     P6: A0(t+3)->buf1   P7: B0(t+3)->buf1   P8: B1(t+3)->buf1 + vmcnt(6)
//   vmcnt(6) at P4 certifies all 4 halves of tile t+1 (buf1); at P8 all of
//   tile t+2 (buf0).  WAR: every stage lands >= 1 full barrier after its
//   region's last ds_read (reads complete at the lgkmcnt(0) before the MFMA
//   preceding that barrier) — verified per phase incl. clamped tail.
// ---------------------------------------------------------------------------

#define BAR()   __builtin_amdgcn_s_barrier()
#define WAITL() do { asm volatile("s_waitcnt lgkmcnt(0)" ::: "memory"); \
                     __builtin_amdgcn_sched_barrier(0); } while (0)
#define WAITL8() asm volatile("s_waitcnt lgkmcnt(8)" ::: "memory")
#define WAITV6() asm volatile("s_waitcnt vmcnt(6)" ::: "memory")
#define PRHI()  __builtin_amdgcn_s_setprio(1)
#define PRLO()  __builtin_amdgcn_s_setprio(0)

#define STAGE_A(t, h, buf) do {                                                   \
    _Pragma("unroll")                                                             \
    for (int c_ = 0; c_ < 2; ++c_)                                                \
        gload_lds16(aG + (size_t)((h) * 128 + prow[c_]) * K_DIM + (t) * BK + pcl[c_] * 8, \
                    As + (buf) * (BM * BK) + (h) * 8192 + c_ * 4096 + tid * 8);   \
} while (0)

#define STAGE_B(t, h, buf) do {                                                   \
    _Pragma("unroll")                                                             \
    for (int c_ = 0; c_ < 2; ++c_)                                                \
        gload_lds16(bG + (size_t)((h) * 128 + prow[c_]) * K_DIM + (t) * BK + pcl[c_] * 8, \
                    Bs + (buf) * (BN * BK) + (h) * 8192 + c_ * 4096 + tid * 8);   \
} while (0)

// Fragment loads: adA/adB hold LDS byte addresses (buf0); buf1 via offset:32768.
// ks=1 sub-chunk differs by XOR 64 bytes (chunk-bit-2 of the swizzled layout).
#define RD_A(grp, buf) do {                                                       \
    _Pragma("unroll")                                                             \
    for (int q_ = 0; q_ < 4; ++q_) {                                              \
        af[q_][0] = DSR(adA[(grp) + q_],       (buf));                            \
        af[q_][1] = DSR(adA[(grp) + q_] ^ 64u, (buf));                            \
    }                                                                             \
} while (0)

#define RD_B(dst, jlo, buf) do {                                                  \
    _Pragma("unroll")                                                             \
    for (int q_ = 0; q_ < 2; ++q_) {                                              \
        dst[q_][0] = DSR(adB[(jlo) + q_],       (buf));                           \
        dst[q_][1] = DSR(adB[(jlo) + q_] ^ 64u, (buf));                           \
    }                                                                             \
} while (0)

#define MMQ(I0, J0, BF) do {                                                      \
    _Pragma("unroll")                                                             \
    for (int q_ = 0; q_ < 4; ++q_)                                                \
        _Pragma("unroll")                                                         \
        for (int jj_ = 0; jj_ < 2; ++jj_)                                         \
            _Pragma("unroll")                                                     \
            for (int ks_ = 0; ks_ < 2; ++ks_)                                     \
                acc[(I0) + q_][(J0) + jj_] = __builtin_amdgcn_mfma_f32_16x16x32_bf16( \
                    af[q_][ks_], BF[jj_][ks_], acc[(I0) + q_][(J0) + jj_], 0, 0, 0);  \
} while (0)

__global__ __launch_bounds__(512, 2)
void gemm_bf16_kernel(const bf16* __restrict__ A,   // [M][K]
                      const bf16* __restrict__ Bt,  // [N][K]
                      float* __restrict__ C) {      // [M][N]
    __shared__ __align__(16) bf16 As[2 * BM * BK];  // 64 KB (2 bufs x 256x64)
    __shared__ __align__(16) bf16 Bs[2 * BN * BK];  // 64 KB

    const int tid  = threadIdx.x;        // 0..511
    const int lane = tid & 63;
    const int wave = tid >> 6;           // 0..7
    const int wm   = (wave >> 2) * 64;   // 0 / 64
    const int wn   = (wave & 3) * 32;    // 0 / 32 / 64 / 96

    // T1: XCD-aware swizzle over the 32x32 block grid (1024 % 8 == 0)
    const int id  = blockIdx.y * 32 + blockIdx.x;
    const int swz = (id & 7) * 128 + (id >> 3);
    const int m0  = (swz >> 5) * BM;
    const int n0  = (swz & 31) * BN;

    // staging descriptors: physical chunk cp at (row,cp) holds k-chunk cp^(row&7)
    int prow[2], pcl[2];
    #pragma unroll
    for (int c = 0; c < 2; ++c) {
        int p   = c * 8192 + tid * 16;   // byte pos within a 16 KB half-tile
        prow[c] = p >> 7;                // 128 B per row
        pcl[c]  = ((p >> 4) & 7) ^ (prow[c] & 7);
    }
    const bf16* aG = A  + (size_t)m0 * K_DIM;
    const bf16* bG = Bt + (size_t)n0 * K_DIM;

    // fragment LDS byte addresses (buf0); ks=0 chunk = (lane>>4) ^ (row&7)
    const unsigned asBase = (unsigned)(uintptr_t)((as3_void)(As));
    const unsigned bsBase = (unsigned)(uintptr_t)((as3_void)(Bs));
    unsigned adA[8], adB[4];
    #pragma unroll
    for (int i = 0; i < 8; ++i) {
        int ra = ((i & 4) ? 128 : 0) + wm + (i & 3) * 16 + (lane & 15);
        adA[i] = asBase + 2u * (unsigned)(ra * 64 + (((lane >> 4) ^ (ra & 7)) * 8));
    }
    #pragma unroll
    for (int j = 0; j < 4; ++j) {
        int rb = ((j & 2) ? 128 : 0) + wn + (j & 1) * 16 + (lane & 15);
        adB[j] = bsBase + 2u * (unsigned)(rb * 64 + (((lane >> 4) ^ (rb & 7)) * 8));
    }

    f32x4 acc[8][4] = {};
    bf16x8 af[4][2], bA[2][2], bBv[2][2];

    // prologue: tile0 (4 halves) + tile1 A0,B0,B1 = 7 half-tiles, 14 loads.
    // vmcnt(6) certifies tile0; tile1's 3 staged halves stay in flight.
    STAGE_A(0, 0, 0); STAGE_B(0, 0, 0);
    STAGE_B(0, 1, 0); STAGE_A(0, 1, 0);
    STAGE_A(1, 0, 1); STAGE_B(1, 0, 1); STAGE_B(1, 1, 1);
    WAITV6();
    BAR();

    for (int it = 0; it < NT / 2; ++it) {
        const int t1 = 2 * it + 1;
        const int t2 = (2 * it + 2 < NT) ? 2 * it + 2 : NT - 1;
        const int t3 = (2 * it + 3 < NT) ? 2 * it + 3 : NT - 1;

        // ---------------- tile 2it from buf0 ----------------
        // P1: Q1 = A0 x B0
        RD_A(0, 0); RD_B(bA, 0, 0);
        STAGE_A(t1, 1, 1);                 // A1(t+1) -> buf1
        WAITL8();
        BAR(); WAITL(); PRHI(); MMQ(0, 0, bA); PRLO(); BAR();
        // P2: Q2 = A0 x B1
        RD_B(bBv, 2, 0);
        STAGE_A(t2, 0, 0);                 // A0(t+2) -> buf0
        BAR(); WAITL(); PRHI(); MMQ(0, 2, bBv); PRLO(); BAR();
        // P3: Q3 = A1 x B0
        RD_A(4, 0);
        STAGE_B(t2, 0, 0);                 // B0(t+2) -> buf0
        BAR(); WAITL(); PRHI(); MMQ(4, 0, bA); PRLO(); BAR();
        // P4: Q4 = A1 x B1 (no new ds_reads)
        STAGE_B(t2, 1, 0);                 // B1(t+2) -> buf0
        WAITV6();                          // certifies all 4 halves of tile t+1
        BAR(); PRHI(); MMQ(4, 2, bBv); PRLO(); BAR();

        // ---------------- tile 2it+1 from buf1 ----------------
        // P5: Q1
        RD_A(0, 1); RD_B(bA, 0, 1);
        STAGE_A(t2, 1, 0);                 // A1(t+2) -> buf0
        WAITL8();
        BAR(); WAITL(); PRHI(); MMQ(0, 0, bA); PRLO(); BAR();
        // P6: Q2
        RD_B(bBv, 2, 1);
        STAGE_A(t3, 0, 1);                 // A0(t+3) -> buf1
        BAR(); WAITL(); PRHI(); MMQ(0, 2, bBv); PRLO(); BAR();
        // P7: Q3
        RD_A(4, 1);
        STAGE_B(t3, 0, 1);                 // B0(t+3) -> buf1
        BAR(); WAITL(); PRHI(); MMQ(4, 0, bA); PRLO(); BAR();
        // P8: Q4
        STAGE_B(t3, 1, 1);                 // B1(t+3) -> buf1
        WAITV6();                          // certifies all 4 halves of tile t+2
        BAR(); PRHI(); MMQ(4, 2, bBv); PRLO(); BAR();
    }

    // epilogue: C/D layout col = lane&15, row = (lane>>4)*4 + reg.
    // Plain (cached) stores: NT stores measured +130 MB WRITE amplification.
    const int cr = (lane >> 4) * 4;
    const int cc = lane & 15;
    #pragma unroll
    for (int i = 0; i < 8; ++i) {
        const int row = m0 + ((i & 4) ? 128 : 0) + wm + (i & 3) * 16 + cr;
        #pragma unroll
        for (int j = 0; j < 4; ++j) {
            const int col = n0 + ((j & 2) ? 128 : 0) + wn + (j & 1) * 16 + cc;
            float* cp = C + (size_t)row * N_DIM + col;
            #pragma unroll
            for (int r = 0; r < 4; ++r)
                cp[(size_t)r * N_DIM] = acc[i][j][r];
        }
    }
}

// ---------------------------------------------------------------------------
extern "C" void kernel_launch(void* const* d_in, const int* in_sizes, int n_in,
                              void* d_out, int out_size, void* d_ws, size_t ws_size,
                              hipStream_t stream) {
    const float* x  = (const float*)d_in[0];   // [B,T,D] = [8192, 2048]
    const float* w  = (const float*)d_in[1];   // [D, F]  = [2048, 8192]
    const float* la = (const float*)d_in[2];   // [D, 16]
    const float* lb = (const float*)d_in[3];   // [16, F]
    float* out = (float*)d_out;                // [8192, 8192]

    bf16* xb = (bf16*)d_ws;                                        // 32 MB
    bf16* wt = (bf16*)((char*)d_ws + (size_t)M_DIM * K_DIM * 2);   // 32 MB

    convert_x_kernel<<<M_DIM * K_DIM / 4 / 256, 256, 0, stream>>>(x, xb);
    fold_transpose_kernel<<<dim3(K_DIM / 32, N_DIM / 32), 256, 0, stream>>>(w, la, lb, wt);
    gemm_bf16_kernel<<<dim3(N_DIM / BN, M_DIM / BM), 512, 0, stream>>>(xb, wt, out);
}